// Round 8
// baseline (557.354 us; speedup 1.0000x reference)
//
#include <hip/hip_runtime.h>
#include <hip/hip_bf16.h>
#include <math.h>

#define CIN   512
#define COUT  512
#define NB    16
#define WD    512
#define HIN   32
#define RES   64
#define LRELU 0.2f
#define ACT_GAIN 1.4142135623730951f

typedef __attribute__((ext_vector_type(8))) short short8;
typedef __attribute__((ext_vector_type(4))) float float4v;
typedef __attribute__((ext_vector_type(16))) float float16v;

// ---------------- styles = w @ A^T / sqrt(512) + bias ----------------
__global__ void styles2_kernel(const float* __restrict__ w,
                               const float* __restrict__ aw,
                               const float* __restrict__ ab,
                               float* __restrict__ styles) {
    int b = blockIdx.x;          // 16
    int cig = blockIdx.y;        // 8
    int lane = threadIdx.x & 63, wv = threadIdx.x >> 6;
    __shared__ float wsh[WD];
    for (int e = threadIdx.x; e < WD; e += 256) wsh[e] = w[b * WD + e];
    __syncthreads();
    for (int r = 0; r < 16; ++r) {
        int ci = cig * 64 + wv * 16 + r;
        const float* arow = aw + (size_t)ci * WD;
        float acc = 0.f;
        for (int k = lane; k < WD; k += 64) acc += arow[k] * wsh[k];
        for (int off = 32; off; off >>= 1) acc += __shfl_down(acc, off, 64);
        if (lane == 0)
            styles[b * CIN + ci] = acc * 0.04419417382415922f + ab[ci];
    }
}

// ---- weights: wsq fp32 + POLYPHASE composite pack ----
// g[phy][phx][dy][dx] = sum_{ay,ax} w[ay][ax] * cr[phy][dy][ay] * cr[phx][dx][ax]
// (cr = flipped-weight x upfirdn coefficient tables, verified on 1D impulses)
// gb layout: [cc16][ph4][t9][chi4][cout512][clo8] bf16
__global__ void prep_weights(const float* __restrict__ weight,
                             float* __restrict__ wsq,
                             __hip_bfloat16* __restrict__ gb) {
    int idx = blockIdx.x * 256 + threadIdx.x;   // 262144
    int co = idx & (COUT - 1);
    int ci = idx >> 9;
    const float* wp = weight + ((size_t)co * CIN + ci) * 9;
    float wv[3][3];
    float s = 0.f;
#pragma unroll
    for (int ay = 0; ay < 3; ++ay)
#pragma unroll
        for (int ax = 0; ax < 3; ++ax) {
            float v = wp[ay * 3 + ax];
            wv[ay][ax] = v;
            s += v * v;
        }
    wsq[(size_t)co * CIN + ci] = s;

    const float cr[2][3][3] = {
        {{0.f, 0.25f, 0.75f}, {0.75f, 0.75f, 0.25f}, {0.25f, 0.f, 0.f}},
        {{0.f, 0.f, 0.25f},  {0.25f, 0.75f, 0.75f}, {0.75f, 0.25f, 0.f}}};

    int cc = ci >> 5, chi = (ci >> 3) & 3, clo = ci & 7;
#pragma unroll
    for (int phy = 0; phy < 2; ++phy) {
        float tmp[3][3];   // tmp[dy][ax] = sum_ay cr[phy][dy][ay] * w[ay][ax]
#pragma unroll
        for (int dy = 0; dy < 3; ++dy)
#pragma unroll
            for (int ax = 0; ax < 3; ++ax)
                tmp[dy][ax] = cr[phy][dy][0] * wv[0][ax]
                            + cr[phy][dy][1] * wv[1][ax]
                            + cr[phy][dy][2] * wv[2][ax];
#pragma unroll
        for (int phx = 0; phx < 2; ++phx) {
            int ph = phy * 2 + phx;
#pragma unroll
            for (int dy = 0; dy < 3; ++dy)
#pragma unroll
                for (int dx = 0; dx < 3; ++dx) {
                    float g = tmp[dy][0] * cr[phx][dx][0]
                            + tmp[dy][1] * cr[phx][dx][1]
                            + tmp[dy][2] * cr[phx][dx][2];
                    int t = dy * 3 + dx;
                    gb[((((size_t)cc * 4 + ph) * 9 + t) * 4 + chi) * (COUT * 8)
                       + (size_t)co * 8 + clo] = __float2bfloat16(g);
                }
        }
    }
}

// ---------------- dcoef[b,co] = rsqrt( sum_ci wsq[co,ci]*styles^2 + 1e-8 ) ----------------
__global__ void dcoef2_kernel(const float* __restrict__ styles,
                              const float* __restrict__ wsq,
                              float* __restrict__ dcoef) {
    int b = blockIdx.x;          // 16
    int cog = blockIdx.y;        // 8
    int lane = threadIdx.x & 63, wv = threadIdx.x >> 6;
    __shared__ float s2[CIN];
    for (int e = threadIdx.x; e < CIN; e += 256) {
        float s = styles[b * CIN + e];
        s2[e] = s * s;
    }
    __syncthreads();
    for (int r = 0; r < 16; ++r) {
        int co = cog * 64 + wv * 16 + r;
        const float* qrow = wsq + (size_t)co * CIN;
        float acc = 0.f;
        for (int k = lane; k < CIN; k += 64) acc += qrow[k] * s2[k];
        for (int off = 32; off; off >>= 1) acc += __shfl_down(acc, off, 64);
        if (lane == 0) dcoef[b * COUT + co] = rsqrtf(acc + 1e-8f);
    }
}

// ------- x * styles -> channels-last bf16 with zero-padded 34x34 border -------
// xb[b][row(34)][col(34)][ci(512)]; row/col = coarse+1, borders zero.
__global__ void xmod_kernel(const float* __restrict__ x,
                            const float* __restrict__ styles,
                            __hip_bfloat16* __restrict__ xb) {
    __shared__ float xt[128 * 36];
    __shared__ float ssh[128];
    const int r = blockIdx.x;         // 0..33 padded row
    const int ci0 = blockIdx.y * 128; // 4 groups
    const int b = blockIdx.z;
    if (threadIdx.x < 128) ssh[threadIdx.x] = styles[b * CIN + ci0 + threadIdx.x];
    const bool inr = (r >= 1) && (r <= 32);
    if (inr) {
        for (int e = threadIdx.x; e < 1024; e += 256) {
            int ci = e >> 3, iw4 = e & 7;
            float4v v = *(const float4v*)(
                x + ((size_t)(b * CIN + ci0 + ci) * HIN + (r - 1)) * HIN + iw4 * 4);
            *(float4v*)(&xt[ci * 36 + iw4 * 4]) = v;
        }
    }
    __syncthreads();
    for (int e = threadIdx.x; e < 544; e += 256) {   // 34 cols * 16 chunks
        int c = e >> 4, t16 = e & 15;
        short8 sv;
#pragma unroll
        for (int u = 0; u < 8; ++u) {
            int ci = t16 * 8 + u;
            float val = 0.f;
            if (inr && c >= 1 && c <= 32) val = xt[ci * 36 + (c - 1)] * ssh[ci];
            __hip_bfloat16 h = __float2bfloat16(val);
            sv[u] = *reinterpret_cast<const short*>(&h);
        }
        *reinterpret_cast<short8*>(
            xb + (((size_t)b * 34 + r) * 34 + c) * CIN + ci0 + t16 * 8) = sv;
    }
}

// ---------------- polyphase implicit-GEMM conv via MFMA bf16 32x32x16 ----------------
// grid (mb2, nb8, b*4+ph): block = one phase, 16 coarse rows x 32 cols (M=512), N=64.
// 8 waves; wave = 2 coarse rows (2x 32x32 m-frags) x 64 couts. A = padded x tile
// [cr18][chi4][col34][8] bf16 = 39168 B (39x1KB slices); B = [t9][chi4][n64][8] = 36864 B.
// Double-buffered, R6 2-slot SGB-pipelined compute.
#define ABUF 39936
#define BBUF 36864
#define BUFSZ (ABUF + BBUF)          // 76800
#define LDS_TOT (2 * BUFSZ)          // 153600 <= 163840

__global__ __launch_bounds__(512, 1) void conv_mfma(
        const __hip_bfloat16* __restrict__ xb,
        const __hip_bfloat16* __restrict__ gb,
        const float* __restrict__ dcoef,
        const float* __restrict__ bias,
        const float* __restrict__ noise,
        const float* __restrict__ nstr,
        float* __restrict__ out)
{
    extern __shared__ __align__(16) char smem[];
    const int tid = threadIdx.x;
    const int lane = tid & 63;
    const int wid = tid >> 6;        // 0..7
    const int li32 = lane & 31;
    const int hi = lane >> 5;        // 0..1
    const int mb = blockIdx.x;       // 0..1 -> coarse rows y0..y0+15
    const int n0 = blockIdx.y * 64;  // cout base
    const int bz = blockIdx.z;       // b*4 + ph
    const int b  = bz >> 2;
    const int ph = bz & 3;
    const int phy = ph >> 1, phx = ph & 1;
    const int y0 = mb * 16;          // padded-row base AND coarse output base

    // ---- staging descriptors ----
    // A: 39 slices of 1KB (2448 granules + pad); wave w takes n = w + k*8 (n<39)
    int a_goff[5];
#pragma unroll
    for (int k = 0; k < 5; ++k) {
        int n = wid + k * 8;
        int s = n * 64 + lane;          // 16B granule id, valid 0..2447
        if (s > 2447) s = 2447;         // clamp global addr (LDS lands in pad)
        int cr = s / 136;
        int rem = s - cr * 136;
        int chi = rem / 34;
        int col = rem - chi * 34;
        a_goff[k] = (((b * 34 + y0 + cr) * 34 + col)) * CIN + chi * 8;
    }
    // B: 36 slices of 1KB; wave w takes sl = w + k*8 (sl<36)
    int b_goff[5];
#pragma unroll
    for (int k = 0; k < 5; ++k) {
        int sl = wid + k * 8;           // t = sl>>2, chi = sl&3
        b_goff[k] = (sl * COUT + n0 + lane) * 8;
    }

    float16v acc[2][2];
#pragma unroll
    for (int i = 0; i < 2; ++i)
#pragma unroll
        for (int j = 0; j < 2; ++j) acc[i][j] = (float16v)0.f;

    const char* xg = (const char*)xb;
    const char* wg = (const char*)gb;

#define STAGE(CC, BUFB) do {                                                  \
        _Pragma("unroll")                                                     \
        for (int k = 0; k < 5; ++k) {                                         \
            int sl = wid + k * 8;                                             \
            if (sl < 36) {                                                    \
                long ge = (long)b_goff[k] + (long)((CC) * 4 + ph) * 147456;   \
                __builtin_amdgcn_global_load_lds(                             \
                    (const __attribute__((address_space(1))) char*)(wg + ge * 2), \
                    (__attribute__((address_space(3))) char*)(smem + (BUFB) + ABUF + sl * 1024), \
                    16, 0, 0);                                                \
            }                                                                 \
        }                                                                     \
        _Pragma("unroll")                                                     \
        for (int k = 0; k < 5; ++k) {                                         \
            int n = wid + k * 8;                                              \
            if (n < 39) {                                                     \
                long ge = (long)(a_goff[k] + (CC) * 32);                      \
                __builtin_amdgcn_global_load_lds(                             \
                    (const __attribute__((address_space(1))) char*)(xg + ge * 2), \
                    (__attribute__((address_space(3))) char*)(smem + (BUFB) + n * 1024), \
                    16, 0, 0);                                                \
            }                                                                 \
        }                                                                     \
    } while (0)

// load the 4 fragments of step S (t = S/2, ks = S&1) into slot SLOT
#define LOADF(BUFB, S, SLOT) do {                                             \
        const int t_ = (S) >> 1, ks_ = (S) & 1;                               \
        const int dy1 = t_ / 3, dx1 = t_ - dy1 * 3;                           \
        _Pragma("unroll")                                                     \
        for (int nf = 0; nf < 2; ++nf)                                        \
            fB[SLOT][nf] = *(const short8*)(smem + (BUFB) + ABUF +            \
                    (((t_ * 4 + ks_ * 2 + hi) * 64) + nf * 32 + li32) * 16);  \
        _Pragma("unroll")                                                     \
        for (int mf = 0; mf < 2; ++mf)                                        \
            fA[SLOT][mf] = *(const short8*)(smem + (BUFB) +                   \
                    ((((wid * 2 + mf + dy1) * 4 + ks_ * 2 + hi) * 34) +       \
                     (li32 + dx1)) * 16);                                     \
    } while (0)

#define COMPUTE(BUFB) do {                                                    \
        short8 fA[2][2], fB[2][2];                                            \
        LOADF(BUFB, 0, 0);                                                    \
        __builtin_amdgcn_sched_group_barrier(0x100, 4, 0); /* DS4: step0 */   \
        __builtin_amdgcn_s_setprio(1);                                        \
        _Pragma("unroll")                                                     \
        for (int s = 0; s < 18; ++s) {                                        \
            const int cur = s & 1, nxt = cur ^ 1;                             \
            if (s < 17) LOADF(BUFB, s + 1, nxt);                              \
            _Pragma("unroll")                                                 \
            for (int mf = 0; mf < 2; ++mf)                                    \
                _Pragma("unroll")                                             \
                for (int nf = 0; nf < 2; ++nf)                                \
                    acc[mf][nf] = __builtin_amdgcn_mfma_f32_32x32x16_bf16(    \
                        fA[cur][mf], fB[cur][nf], acc[mf][nf], 0, 0, 0);      \
            if (s < 17)                                                       \
                __builtin_amdgcn_sched_group_barrier(0x100, 4, 0); /* DS4 n+1 */ \
            __builtin_amdgcn_sched_group_barrier(0x008, 4, 0);     /* MFMA4 n */ \
        }                                                                     \
        __builtin_amdgcn_s_setprio(0);                                        \
    } while (0)

#define SYNC() do {                                                           \
        asm volatile("s_waitcnt vmcnt(0)" ::: "memory");                      \
        __builtin_amdgcn_s_barrier();                                         \
    } while (0)

    // prologue: stage cc=0 into buf0
    STAGE(0, 0);
    SYNC();

#pragma unroll 1
    for (int cc = 0; cc < 16; cc += 2) {
        STAGE(cc + 1, BUFSZ);        // issue early: latency hides under taps
        COMPUTE(0);
        SYNC();                      // drain (cheap) + one barrier
        if (cc + 2 < 16) STAGE(cc + 2, 0);
        COMPUTE(BUFSZ);
        SYNC();
    }

#undef STAGE
#undef LOADF
#undef COMPUTE
#undef SYNC

    // ---- epilogue: *dcoef + noise + bias -> lrelu*gain (fine grid, stride-2) ----
    const float ns = nstr[0];
#pragma unroll
    for (int nf = 0; nf < 2; ++nf) {
        int cout = n0 + nf * 32 + li32;
        float dc = dcoef[b * COUT + cout];
        float bs = bias[cout];
#pragma unroll
        for (int mf = 0; mf < 2; ++mf) {
            int ic = y0 + wid * 2 + mf;      // coarse row
            int fr = 2 * ic + phy;           // fine row
            float* op = out + ((size_t)(b * COUT + cout) * RES + fr) * RES;
            const float* npz = noise + fr * RES;
#pragma unroll
            for (int r2 = 0; r2 < 4; ++r2) {
#pragma unroll
                for (int u = 0; u < 4; ++u) {
                    int j = 8 * r2 + 4 * hi + u;   // coarse col
                    int fc = 2 * j + phx;          // fine col
                    float v = acc[mf][nf][r2 * 4 + u] * dc + npz[fc] * ns + bs;
                    v = (v > 0.f ? v : LRELU * v) * ACT_GAIN;
                    op[fc] = v;
                }
            }
        }
    }
}

extern "C" void kernel_launch(void* const* d_in, const int* in_sizes, int n_in,
                              void* d_out, int out_size, void* d_ws, size_t ws_size,
                              hipStream_t stream) {
    (void)in_sizes; (void)n_in; (void)out_size; (void)ws_size;
    const float* x     = (const float*)d_in[0];
    const float* w     = (const float*)d_in[1];
    const float* aw    = (const float*)d_in[2];
    const float* ab    = (const float*)d_in[3];
    const float* wt    = (const float*)d_in[4];
    const float* bias  = (const float*)d_in[5];
    const float* noise = (const float*)d_in[6];
    const float* nstr  = (const float*)d_in[7];
    float* out = (float*)d_out;

    static bool init = false;
    if (!init) {
        hipFuncSetAttribute(reinterpret_cast<const void*>(conv_mfma),
                            hipFuncAttributeMaxDynamicSharedMemorySize, LDS_TOT);
        init = true;
    }

    char* ws = (char*)d_ws;
    float* styles = (float*)ws;                                   // 32 KB
    float* dcoef  = (float*)(ws + 32768);                         // 32 KB
    float* wsq    = (float*)(ws + 65536);                         // 1 MB
    __hip_bfloat16* gb = (__hip_bfloat16*)(ws + 65536 + 1048576);           // 18.87 MB
    __hip_bfloat16* xb = (__hip_bfloat16*)(ws + 65536 + 1048576 + 18874368); // 18.94 MB

    styles2_kernel<<<dim3(NB, 8), dim3(256), 0, stream>>>(w, aw, ab, styles);
    prep_weights<<<dim3(1024), dim3(256), 0, stream>>>(wt, wsq, gb);
    dcoef2_kernel<<<dim3(NB, 8), dim3(256), 0, stream>>>(styles, wsq, dcoef);
    xmod_kernel<<<dim3(34, 4, NB), dim3(256), 0, stream>>>(x, styles, xb);
    conv_mfma<<<dim3(2, 8, NB * 4), dim3(512), LDS_TOT, stream>>>(
        xb, gb, dcoef, bias, noise, nstr, out);
}

// Round 9
// 494.740 us; speedup vs baseline: 1.1266x; 1.1266x over previous
//
#include <hip/hip_runtime.h>
#include <hip/hip_bf16.h>
#include <math.h>

#define CIN   512
#define COUT  512
#define NB    16
#define WD    512
#define HIN   32
#define RES   64
#define LRELU 0.2f
#define ACT_GAIN 1.4142135623730951f

typedef __attribute__((ext_vector_type(8))) short short8;
typedef __attribute__((ext_vector_type(4))) float float4v;
typedef __attribute__((ext_vector_type(16))) float float16v;

// ---------------- styles = w @ A^T / sqrt(512) + bias ----------------
__global__ void styles2_kernel(const float* __restrict__ w,
                               const float* __restrict__ aw,
                               const float* __restrict__ ab,
                               float* __restrict__ styles) {
    int b = blockIdx.x;          // 16
    int cig = blockIdx.y;        // 8
    int lane = threadIdx.x & 63, wv = threadIdx.x >> 6;
    __shared__ float wsh[WD];
    for (int e = threadIdx.x; e < WD; e += 256) wsh[e] = w[b * WD + e];
    __syncthreads();
    for (int r = 0; r < 16; ++r) {
        int ci = cig * 64 + wv * 16 + r;
        const float* arow = aw + (size_t)ci * WD;
        float acc = 0.f;
        for (int k = lane; k < WD; k += 64) acc += arow[k] * wsh[k];
        for (int off = 32; off; off >>= 1) acc += __shfl_down(acc, off, 64);
        if (lane == 0)
            styles[b * CIN + ci] = acc * 0.04419417382415922f + ab[ci];
    }
}

// ---- weights: wsq fp32 + POLYPHASE composite pack (coalesced short8 stores) ----
// g[phy][phx][dy][dx] = sum_{ay,ax} w[ay][ax] * cr[phy][dy][ay] * cr[phx][dx][ax]
// gb layout: [cc16][phy2][t9][chi4][cog16][n64][clo8] bf16, n = phx*32 + colo.
// One thread handles all 8 clo of (co, cc, chi) -> every store is 16B short8,
// contiguous across consecutive-co lanes (full coalescing).
__global__ void prep_weights(const float* __restrict__ weight,
                             float* __restrict__ wsq,
                             __hip_bfloat16* __restrict__ gb) {
    int gid = blockIdx.x * 256 + threadIdx.x;   // 32768
    int co = gid & 511;
    int cig = gid >> 9;          // 0..63
    int cc = cig >> 2, chi = cig & 3;
    int cib = cc * 32 + chi * 8;
    int cog = co >> 5, colo = co & 31;

    float wv[8][3][3];
#pragma unroll
    for (int clo = 0; clo < 8; ++clo) {
        const float* wp = weight + ((size_t)co * CIN + cib + clo) * 9;
        float s = 0.f;
#pragma unroll
        for (int ay = 0; ay < 3; ++ay)
#pragma unroll
            for (int ax = 0; ax < 3; ++ax) {
                float v = wp[ay * 3 + ax];
                wv[clo][ay][ax] = v;
                s += v * v;
            }
        wsq[(size_t)co * CIN + cib + clo] = s;
    }

    const float cr[2][3][3] = {
        {{0.f, 0.25f, 0.75f}, {0.75f, 0.75f, 0.25f}, {0.25f, 0.f, 0.f}},
        {{0.f, 0.f, 0.25f},  {0.25f, 0.75f, 0.75f}, {0.75f, 0.25f, 0.f}}};

#pragma unroll
    for (int phy = 0; phy < 2; ++phy) {
        float tmp[8][3][3];   // tmp[clo][dy][ax] = sum_ay cr[phy][dy][ay]*wv[clo][ay][ax]
#pragma unroll
        for (int clo = 0; clo < 8; ++clo)
#pragma unroll
            for (int dy = 0; dy < 3; ++dy)
#pragma unroll
                for (int ax = 0; ax < 3; ++ax)
                    tmp[clo][dy][ax] = cr[phy][dy][0] * wv[clo][0][ax]
                                     + cr[phy][dy][1] * wv[clo][1][ax]
                                     + cr[phy][dy][2] * wv[clo][2][ax];
#pragma unroll
        for (int phx = 0; phx < 2; ++phx) {
            int n = phx * 32 + colo;
#pragma unroll
            for (int dy = 0; dy < 3; ++dy)
#pragma unroll
                for (int dx = 0; dx < 3; ++dx) {
                    int t = dy * 3 + dx;
                    short8 sv;
#pragma unroll
                    for (int clo = 0; clo < 8; ++clo) {
                        float g = tmp[clo][dy][0] * cr[phx][dx][0]
                                + tmp[clo][dy][1] * cr[phx][dx][1]
                                + tmp[clo][dy][2] * cr[phx][dx][2];
                        __hip_bfloat16 h = __float2bfloat16(g);
                        sv[clo] = *reinterpret_cast<const short*>(&h);
                    }
                    size_t off = ((((((size_t)cc * 2 + phy) * 9 + t) * 4 + chi)
                                   * 16 + cog) * 64 + n) * 8;
                    *reinterpret_cast<short8*>(gb + off) = sv;
                }
        }
    }
}

// ---------------- dcoef[b,co] = rsqrt( sum_ci wsq[co,ci]*styles^2 + 1e-8 ) ----------------
__global__ void dcoef2_kernel(const float* __restrict__ styles,
                              const float* __restrict__ wsq,
                              float* __restrict__ dcoef) {
    int b = blockIdx.x;          // 16
    int cog = blockIdx.y;        // 8
    int lane = threadIdx.x & 63, wv = threadIdx.x >> 6;
    __shared__ float s2[CIN];
    for (int e = threadIdx.x; e < CIN; e += 256) {
        float s = styles[b * CIN + e];
        s2[e] = s * s;
    }
    __syncthreads();
    for (int r = 0; r < 16; ++r) {
        int co = cog * 64 + wv * 16 + r;
        const float* qrow = wsq + (size_t)co * CIN;
        float acc = 0.f;
        for (int k = lane; k < CIN; k += 64) acc += qrow[k] * s2[k];
        for (int off = 32; off; off >>= 1) acc += __shfl_down(acc, off, 64);
        if (lane == 0) dcoef[b * COUT + co] = rsqrtf(acc + 1e-8f);
    }
}

// ------- x * styles -> channels-last bf16 with zero-padded 34x34 border -------
// xb[b][row(34)][col(34)][ci(512)]; row/col = coarse+1, borders zero.
__global__ void xmod_kernel(const float* __restrict__ x,
                            const float* __restrict__ styles,
                            __hip_bfloat16* __restrict__ xb) {
    __shared__ float xt[128 * 36];
    __shared__ float ssh[128];
    const int r = blockIdx.x;         // 0..33 padded row
    const int ci0 = blockIdx.y * 128; // 4 groups
    const int b = blockIdx.z;
    if (threadIdx.x < 128) ssh[threadIdx.x] = styles[b * CIN + ci0 + threadIdx.x];
    const bool inr = (r >= 1) && (r <= 32);
    if (inr) {
        for (int e = threadIdx.x; e < 1024; e += 256) {
            int ci = e >> 3, iw4 = e & 7;
            float4v v = *(const float4v*)(
                x + ((size_t)(b * CIN + ci0 + ci) * HIN + (r - 1)) * HIN + iw4 * 4);
            *(float4v*)(&xt[ci * 36 + iw4 * 4]) = v;
        }
    }
    __syncthreads();
    for (int e = threadIdx.x; e < 544; e += 256) {   // 34 cols * 16 chunks
        int c = e >> 4, t16 = e & 15;
        short8 sv;
#pragma unroll
        for (int u = 0; u < 8; ++u) {
            int ci = t16 * 8 + u;
            float val = 0.f;
            if (inr && c >= 1 && c <= 32) val = xt[ci * 36 + (c - 1)] * ssh[ci];
            __hip_bfloat16 h = __float2bfloat16(val);
            sv[u] = *reinterpret_cast<const short*>(&h);
        }
        *reinterpret_cast<short8*>(
            xb + (((size_t)b * 34 + r) * 34 + c) * CIN + ci0 + t16 * 8) = sv;
    }
}

// ---------------- polyphase implicit-GEMM conv via MFMA bf16 32x32x16 ----------------
// grid (mb2, cog16, b*2+phy): block = 16 coarse rows x 32 cols (M=512),
// 32 couts x BOTH phx (N=64 frag dim = phx*32+colo). Epilogue interleaves
// the two phx accs in registers -> contiguous 8-float stores, full-line writes
// (fix for R8's 2.9x WRITE amplification from stride-2 scatter).
// A = [cr18][chi4][col34][8] bf16 = 39168 B (39x1KB); B = [t9][chi4][n64][8] = 36864 B.
#define ABUF 39936
#define BBUF 36864
#define BUFSZ (ABUF + BBUF)          // 76800
#define LDS_TOT (2 * BUFSZ)          // 153600 <= 163840

__global__ __launch_bounds__(512, 1) void conv_mfma(
        const __hip_bfloat16* __restrict__ xb,
        const __hip_bfloat16* __restrict__ gb,
        const float* __restrict__ dcoef,
        const float* __restrict__ bias,
        const float* __restrict__ noise,
        const float* __restrict__ nstr,
        float* __restrict__ out)
{
    extern __shared__ __align__(16) char smem[];
    const int tid = threadIdx.x;
    const int lane = tid & 63;
    const int wid = tid >> 6;        // 0..7
    const int li32 = lane & 31;
    const int hi = lane >> 5;        // 0..1
    const int mb = blockIdx.x;       // 0..1 -> coarse rows y0..y0+15
    const int cog = blockIdx.y;      // 0..15 -> couts cog*32..+31
    const int bz = blockIdx.z;       // b*2 + phy
    const int b  = bz >> 1;
    const int phy = bz & 1;
    const int y0 = mb * 16;          // padded-row base AND coarse output base

    // ---- staging descriptors ----
    // A: 39 slices of 1KB (2448 granules + pad); wave w takes n = w + k*8 (n<39)
    int a_goff[5];
#pragma unroll
    for (int k = 0; k < 5; ++k) {
        int n = wid + k * 8;
        int s = n * 64 + lane;          // 16B granule id, valid 0..2447
        if (s > 2447) s = 2447;         // clamp global addr (LDS lands in pad)
        int cr = s / 136;
        int rem = s - cr * 136;
        int chi = rem / 34;
        int col = rem - chi * 34;
        a_goff[k] = (((b * 34 + y0 + cr) * 34 + col)) * CIN + chi * 8;
    }
    // B: 36 slices of 1KB; wave w takes sl = w + k*8 (sl<36). Byte offsets.
    int b_goff[5];
#pragma unroll
    for (int k = 0; k < 5; ++k) {
        int sl = wid + k * 8;           // sl = t*4+chi
        b_goff[k] = phy * 589824 + (sl * 16 + cog) * 1024 + lane * 16;
    }

    float16v acc[2][2];
#pragma unroll
    for (int i = 0; i < 2; ++i)
#pragma unroll
        for (int j = 0; j < 2; ++j) acc[i][j] = (float16v)0.f;

    const char* xg = (const char*)xb;
    const char* wg = (const char*)gb;

#define STAGE(CC, BUFB) do {                                                  \
        _Pragma("unroll")                                                     \
        for (int k = 0; k < 5; ++k) {                                         \
            int sl = wid + k * 8;                                             \
            if (sl < 36) {                                                    \
                long ge = (long)b_goff[k] + (long)(CC) * 1179648;             \
                __builtin_amdgcn_global_load_lds(                             \
                    (const __attribute__((address_space(1))) char*)(wg + ge), \
                    (__attribute__((address_space(3))) char*)(smem + (BUFB) + ABUF + sl * 1024), \
                    16, 0, 0);                                                \
            }                                                                 \
        }                                                                     \
        _Pragma("unroll")                                                     \
        for (int k = 0; k < 5; ++k) {                                         \
            int n = wid + k * 8;                                              \
            if (n < 39) {                                                     \
                long ge = (long)(a_goff[k] + (CC) * 32);                      \
                __builtin_amdgcn_global_load_lds(                             \
                    (const __attribute__((address_space(1))) char*)(xg + ge * 2), \
                    (__attribute__((address_space(3))) char*)(smem + (BUFB) + n * 1024), \
                    16, 0, 0);                                                \
            }                                                                 \
        }                                                                     \
    } while (0)

// load the 4 fragments of step S (t = S/2, ks = S&1) into slot SLOT
#define LOADF(BUFB, S, SLOT) do {                                             \
        const int t_ = (S) >> 1, ks_ = (S) & 1;                               \
        const int dy1 = t_ / 3, dx1 = t_ - dy1 * 3;                           \
        _Pragma("unroll")                                                     \
        for (int nf = 0; nf < 2; ++nf)                                        \
            fB[SLOT][nf] = *(const short8*)(smem + (BUFB) + ABUF +            \
                    (((t_ * 4 + ks_ * 2 + hi) * 64) + nf * 32 + li32) * 16);  \
        _Pragma("unroll")                                                     \
        for (int mf = 0; mf < 2; ++mf)                                        \
            fA[SLOT][mf] = *(const short8*)(smem + (BUFB) +                   \
                    ((((wid * 2 + mf + dy1) * 4 + ks_ * 2 + hi) * 34) +       \
                     (li32 + dx1)) * 16);                                     \
    } while (0)

#define COMPUTE(BUFB) do {                                                    \
        short8 fA[2][2], fB[2][2];                                            \
        LOADF(BUFB, 0, 0);                                                    \
        __builtin_amdgcn_sched_group_barrier(0x100, 4, 0); /* DS4: step0 */   \
        __builtin_amdgcn_s_setprio(1);                                        \
        _Pragma("unroll")                                                     \
        for (int s = 0; s < 18; ++s) {                                        \
            const int cur = s & 1, nxt = cur ^ 1;                             \
            if (s < 17) LOADF(BUFB, s + 1, nxt);                              \
            _Pragma("unroll")                                                 \
            for (int mf = 0; mf < 2; ++mf)                                    \
                _Pragma("unroll")                                             \
                for (int nf = 0; nf < 2; ++nf)                                \
                    acc[mf][nf] = __builtin_amdgcn_mfma_f32_32x32x16_bf16(    \
                        fA[cur][mf], fB[cur][nf], acc[mf][nf], 0, 0, 0);      \
            if (s < 17)                                                       \
                __builtin_amdgcn_sched_group_barrier(0x100, 4, 0); /* DS4 n+1 */ \
            __builtin_amdgcn_sched_group_barrier(0x008, 4, 0);     /* MFMA4 n */ \
        }                                                                     \
        __builtin_amdgcn_s_setprio(0);                                        \
    } while (0)

#define SYNC() do {                                                           \
        asm volatile("s_waitcnt vmcnt(0)" ::: "memory");                      \
        __builtin_amdgcn_s_barrier();                                         \
    } while (0)

    // prologue: stage cc=0 into buf0
    STAGE(0, 0);
    SYNC();

#pragma unroll 1
    for (int cc = 0; cc < 16; cc += 2) {
        STAGE(cc + 1, BUFSZ);        // issue early: latency hides under taps
        COMPUTE(0);
        SYNC();                      // drain (cheap) + one barrier
        if (cc + 2 < 16) STAGE(cc + 2, 0);
        COMPUTE(BUFSZ);
        SYNC();
    }

#undef STAGE
#undef LOADF
#undef COMPUTE
#undef SYNC

    // ---- epilogue: interleave phx0/phx1 accs -> contiguous 8-float stores ----
    const float ns = nstr[0];
    const int cout = cog * 32 + li32;
    const float dc = dcoef[b * COUT + cout];
    const float bs = bias[cout];
#pragma unroll
    for (int mf = 0; mf < 2; ++mf) {
        int ic = y0 + wid * 2 + mf;      // coarse row
        int fr = 2 * ic + phy;           // fine row
        float* op = out + ((size_t)(b * COUT + cout) * RES + fr) * RES;
        const float* npz = noise + fr * RES;
#pragma unroll
        for (int r2 = 0; r2 < 4; ++r2) {
            int fcb = 16 * r2 + 8 * hi;  // fine col base, 8 consecutive
            float nzv[8];
            *(float4v*)&nzv[0] = *(const float4v*)(npz + fcb);
            *(float4v*)&nzv[4] = *(const float4v*)(npz + fcb + 4);
            float f[8];
#pragma unroll
            for (int uu = 0; uu < 4; ++uu) {
#pragma unroll
                for (int nf = 0; nf < 2; ++nf) {
                    float v = acc[mf][nf][r2 * 4 + uu] * dc
                            + nzv[2 * uu + nf] * ns + bs;
                    f[2 * uu + nf] = (v > 0.f ? v : LRELU * v) * ACT_GAIN;
                }
            }
            *(float4v*)(op + fcb)     = *(const float4v*)&f[0];
            *(float4v*)(op + fcb + 4) = *(const float4v*)&f[4];
        }
    }
}

extern "C" void kernel_launch(void* const* d_in, const int* in_sizes, int n_in,
                              void* d_out, int out_size, void* d_ws, size_t ws_size,
                              hipStream_t stream) {
    (void)in_sizes; (void)n_in; (void)out_size; (void)ws_size;
    const float* x     = (const float*)d_in[0];
    const float* w     = (const float*)d_in[1];
    const float* aw    = (const float*)d_in[2];
    const float* ab    = (const float*)d_in[3];
    const float* wt    = (const float*)d_in[4];
    const float* bias  = (const float*)d_in[5];
    const float* noise = (const float*)d_in[6];
    const float* nstr  = (const float*)d_in[7];
    float* out = (float*)d_out;

    static bool init = false;
    if (!init) {
        hipFuncSetAttribute(reinterpret_cast<const void*>(conv_mfma),
                            hipFuncAttributeMaxDynamicSharedMemorySize, LDS_TOT);
        init = true;
    }

    char* ws = (char*)d_ws;
    float* styles = (float*)ws;                                   // 32 KB
    float* dcoef  = (float*)(ws + 32768);                         // 32 KB
    float* wsq    = (float*)(ws + 65536);                         // 1 MB
    __hip_bfloat16* gb = (__hip_bfloat16*)(ws + 65536 + 1048576);           // 18.87 MB
    __hip_bfloat16* xb = (__hip_bfloat16*)(ws + 65536 + 1048576 + 18874368); // 18.94 MB

    styles2_kernel<<<dim3(NB, 8), dim3(256), 0, stream>>>(w, aw, ab, styles);
    prep_weights<<<dim3(128), dim3(256), 0, stream>>>(wt, wsq, gb);
    dcoef2_kernel<<<dim3(NB, 8), dim3(256), 0, stream>>>(styles, wsq, dcoef);
    xmod_kernel<<<dim3(34, 4, NB), dim3(256), 0, stream>>>(x, styles, xb);
    conv_mfma<<<dim3(2, 16, NB * 2), dim3(512), LDS_TOT, stream>>>(
        xb, gb, dcoef, bias, noise, nstr, out);
}

// Round 10
// 488.004 us; speedup vs baseline: 1.1421x; 1.0138x over previous
//
#include <hip/hip_runtime.h>
#include <hip/hip_bf16.h>
#include <math.h>

#define CIN   512
#define COUT  512
#define NB    16
#define WD    512
#define HIN   32
#define RES   64
#define LRELU 0.2f
#define ACT_GAIN 1.4142135623730951f

typedef __attribute__((ext_vector_type(8))) short short8;
typedef __attribute__((ext_vector_type(4))) float float4v;
typedef __attribute__((ext_vector_type(16))) float float16v;

// ---------------- styles = w @ A^T / sqrt(512) + bias ----------------
__global__ void styles2_kernel(const float* __restrict__ w,
                               const float* __restrict__ aw,
                               const float* __restrict__ ab,
                               float* __restrict__ styles) {
    int b = blockIdx.x;          // 16
    int cig = blockIdx.y;        // 8
    int lane = threadIdx.x & 63, wv = threadIdx.x >> 6;
    __shared__ float wsh[WD];
    for (int e = threadIdx.x; e < WD; e += 256) wsh[e] = w[b * WD + e];
    __syncthreads();
    for (int r = 0; r < 16; ++r) {
        int ci = cig * 64 + wv * 16 + r;
        const float* arow = aw + (size_t)ci * WD;
        float acc = 0.f;
        for (int k = lane; k < WD; k += 64) acc += arow[k] * wsh[k];
        for (int off = 32; off; off >>= 1) acc += __shfl_down(acc, off, 64);
        if (lane == 0)
            styles[b * CIN + ci] = acc * 0.04419417382415922f + ab[ci];
    }
}

// ---- weights: wsq fp32 + POLYPHASE composite pack (coalesced short8 stores) ----
// gb layout: [cc16][phy2][t9][chi4][cog16][n64][clo8] bf16, n = phx*32 + colo.
__global__ void prep_weights(const float* __restrict__ weight,
                             float* __restrict__ wsq,
                             __hip_bfloat16* __restrict__ gb) {
    int gid = blockIdx.x * 256 + threadIdx.x;   // 32768
    int co = gid & 511;
    int cig = gid >> 9;          // 0..63
    int cc = cig >> 2, chi = cig & 3;
    int cib = cc * 32 + chi * 8;
    int cog = co >> 5, colo = co & 31;

    float wv[8][3][3];
#pragma unroll
    for (int clo = 0; clo < 8; ++clo) {
        const float* wp = weight + ((size_t)co * CIN + cib + clo) * 9;
        float s = 0.f;
#pragma unroll
        for (int ay = 0; ay < 3; ++ay)
#pragma unroll
            for (int ax = 0; ax < 3; ++ax) {
                float v = wp[ay * 3 + ax];
                wv[clo][ay][ax] = v;
                s += v * v;
            }
        wsq[(size_t)co * CIN + cib + clo] = s;
    }

    const float cr[2][3][3] = {
        {{0.f, 0.25f, 0.75f}, {0.75f, 0.75f, 0.25f}, {0.25f, 0.f, 0.f}},
        {{0.f, 0.f, 0.25f},  {0.25f, 0.75f, 0.75f}, {0.75f, 0.25f, 0.f}}};

#pragma unroll
    for (int phy = 0; phy < 2; ++phy) {
        float tmp[8][3][3];
#pragma unroll
        for (int clo = 0; clo < 8; ++clo)
#pragma unroll
            for (int dy = 0; dy < 3; ++dy)
#pragma unroll
                for (int ax = 0; ax < 3; ++ax)
                    tmp[clo][dy][ax] = cr[phy][dy][0] * wv[clo][0][ax]
                                     + cr[phy][dy][1] * wv[clo][1][ax]
                                     + cr[phy][dy][2] * wv[clo][2][ax];
#pragma unroll
        for (int phx = 0; phx < 2; ++phx) {
            int n = phx * 32 + colo;
#pragma unroll
            for (int dy = 0; dy < 3; ++dy)
#pragma unroll
                for (int dx = 0; dx < 3; ++dx) {
                    int t = dy * 3 + dx;
                    short8 sv;
#pragma unroll
                    for (int clo = 0; clo < 8; ++clo) {
                        float g = tmp[clo][dy][0] * cr[phx][dx][0]
                                + tmp[clo][dy][1] * cr[phx][dx][1]
                                + tmp[clo][dy][2] * cr[phx][dx][2];
                        __hip_bfloat16 h = __float2bfloat16(g);
                        sv[clo] = *reinterpret_cast<const short*>(&h);
                    }
                    size_t off = ((((((size_t)cc * 2 + phy) * 9 + t) * 4 + chi)
                                   * 16 + cog) * 64 + n) * 8;
                    *reinterpret_cast<short8*>(gb + off) = sv;
                }
        }
    }
}

// ---------------- dcoef[b,co] = rsqrt( sum_ci wsq[co,ci]*styles^2 + 1e-8 ) ----------------
__global__ void dcoef2_kernel(const float* __restrict__ styles,
                              const float* __restrict__ wsq,
                              float* __restrict__ dcoef) {
    int b = blockIdx.x;          // 16
    int cog = blockIdx.y;        // 8
    int lane = threadIdx.x & 63, wv = threadIdx.x >> 6;
    __shared__ float s2[CIN];
    for (int e = threadIdx.x; e < CIN; e += 256) {
        float s = styles[b * CIN + e];
        s2[e] = s * s;
    }
    __syncthreads();
    for (int r = 0; r < 16; ++r) {
        int co = cog * 64 + wv * 16 + r;
        const float* qrow = wsq + (size_t)co * CIN;
        float acc = 0.f;
        for (int k = lane; k < CIN; k += 64) acc += qrow[k] * s2[k];
        for (int off = 32; off; off >>= 1) acc += __shfl_down(acc, off, 64);
        if (lane == 0) dcoef[b * COUT + co] = rsqrtf(acc + 1e-8f);
    }
}

// ------- x * styles -> channels-last bf16 with zero-padded 34x34 border -------
__global__ void xmod_kernel(const float* __restrict__ x,
                            const float* __restrict__ styles,
                            __hip_bfloat16* __restrict__ xb) {
    __shared__ float xt[128 * 36];
    __shared__ float ssh[128];
    const int r = blockIdx.x;         // 0..33 padded row
    const int ci0 = blockIdx.y * 128; // 4 groups
    const int b = blockIdx.z;
    if (threadIdx.x < 128) ssh[threadIdx.x] = styles[b * CIN + ci0 + threadIdx.x];
    const bool inr = (r >= 1) && (r <= 32);
    if (inr) {
        for (int e = threadIdx.x; e < 1024; e += 256) {
            int ci = e >> 3, iw4 = e & 7;
            float4v v = *(const float4v*)(
                x + ((size_t)(b * CIN + ci0 + ci) * HIN + (r - 1)) * HIN + iw4 * 4);
            *(float4v*)(&xt[ci * 36 + iw4 * 4]) = v;
        }
    }
    __syncthreads();
    for (int e = threadIdx.x; e < 544; e += 256) {   // 34 cols * 16 chunks
        int c = e >> 4, t16 = e & 15;
        short8 sv;
#pragma unroll
        for (int u = 0; u < 8; ++u) {
            int ci = t16 * 8 + u;
            float val = 0.f;
            if (inr && c >= 1 && c <= 32) val = xt[ci * 36 + (c - 1)] * ssh[ci];
            __hip_bfloat16 h = __float2bfloat16(val);
            sv[u] = *reinterpret_cast<const short*>(&h);
        }
        *reinterpret_cast<short8*>(
            xb + (((size_t)b * 34 + r) * 34 + c) * CIN + ci0 + t16 * 8) = sv;
    }
}

// ---------------- polyphase implicit-GEMM conv via MFMA bf16 32x32x16 ----------------
// R10: wave tile 2 m-frags x 4 n-frags -> 6 ds_reads per 8 MFMAs (was 4/4).
// K-chunk halved to 16 ci so dbuf fits: A [cr18][kh2][col34][8] = 19584 B (20x1KB),
// B [t9][g2][kh2][n64][8] = 36864 B (36x1KB). 32 cc steps.
// grid (mb2, cogp8, b*2+phy32): block = 16 coarse rows x 32 cols, 64 couts x 2 phx.
#define ABUF 20480
#define BBUF 36864
#define BUFSZ (ABUF + BBUF)          // 57344
#define LDS_TOT (2 * BUFSZ)          // 114688 <= 163840

__global__ __launch_bounds__(512, 1) void conv_mfma(
        const __hip_bfloat16* __restrict__ xb,
        const __hip_bfloat16* __restrict__ gb,
        const float* __restrict__ dcoef,
        const float* __restrict__ bias,
        const float* __restrict__ noise,
        const float* __restrict__ nstr,
        float* __restrict__ out)
{
    extern __shared__ __align__(16) char smem[];
    const int tid = threadIdx.x;
    const int lane = tid & 63;
    const int wid = tid >> 6;        // 0..7
    const int li32 = lane & 31;
    const int hi = lane >> 5;        // 0..1
    const int mb = blockIdx.x;       // 0..1 -> coarse rows y0..y0+15
    const int cogp = blockIdx.y;     // 0..7 -> couts cogp*64..+63
    const int bz = blockIdx.z;       // b*2 + phy
    const int b  = bz >> 1;
    const int phy = bz & 1;
    const int y0 = mb * 16;

    // ---- staging descriptors ----
    // A: 20 slices of 1KB (1224 granules + pad); wave w takes n = w + k*8 (n<20)
    int a_goff[3];
#pragma unroll
    for (int k = 0; k < 3; ++k) {
        int n = wid + k * 8;
        int s = n * 64 + lane;          // 16B granule id, valid 0..1223
        if (s > 1223) s = 1223;         // clamp (LDS lands in pad)
        int cr = s / 68;
        int rem = s - cr * 68;
        int kh = rem / 34;
        int col = rem - kh * 34;
        a_goff[k] = ((b * 34 + y0 + cr) * 34 + col) * 512 + kh * 8;
    }
    // B: 36 slices of 1KB; sl = t*4 + g*2 + kh; wave w takes sl = w + k*8 (sl<36)
    int b_goff[5];   // BYTE offsets into gb (cc-independent part)
#pragma unroll
    for (int k = 0; k < 5; ++k) {
        int sl = wid + k * 8;
        int t = sl >> 2, g = (sl >> 1) & 1, kh = sl & 1;
        b_goff[k] = (phy * 9 + t) * 65536 + kh * 16384
                  + (cogp * 2 + g) * 1024 + lane * 16;
    }

    float16v acc[2][4];
#pragma unroll
    for (int i = 0; i < 2; ++i)
#pragma unroll
        for (int j = 0; j < 4; ++j) acc[i][j] = (float16v)0.f;

    const char* xg = (const char*)xb;
    const char* wg = (const char*)gb;

#define STAGE(CC, BUFB) do {                                                  \
        _Pragma("unroll")                                                     \
        for (int k = 0; k < 5; ++k) {                                         \
            int sl = wid + k * 8;                                             \
            if (sl < 36) {                                                    \
                long ge = (long)b_goff[k] + (long)((CC) >> 1) * 1179648       \
                        + (long)((CC) & 1) * 32768;                           \
                __builtin_amdgcn_global_load_lds(                             \
                    (const __attribute__((address_space(1))) char*)(wg + ge), \
                    (__attribute__((address_space(3))) char*)(smem + (BUFB) + ABUF + sl * 1024), \
                    16, 0, 0);                                                \
            }                                                                 \
        }                                                                     \
        _Pragma("unroll")                                                     \
        for (int k = 0; k < 3; ++k) {                                         \
            int n = wid + k * 8;                                              \
            if (n < 20) {                                                     \
                long ge = (long)(a_goff[k] + (CC) * 16);                      \
                __builtin_amdgcn_global_load_lds(                             \
                    (const __attribute__((address_space(1))) char*)(xg + ge * 2), \
                    (__attribute__((address_space(3))) char*)(smem + (BUFB) + n * 1024), \
                    16, 0, 0);                                                \
            }                                                                 \
        }                                                                     \
    } while (0)

// load the 6 fragments of tap T into slot SLOT (2 fA + 4 fB)
#define LOADF(BUFB, T, SLOT) do {                                             \
        const int dy_ = (T) / 3, dx_ = (T) - dy_ * 3;                         \
        _Pragma("unroll")                                                     \
        for (int nf = 0; nf < 4; ++nf) {                                      \
            const int g_ = nf >> 1, px_ = nf & 1;                             \
            fB[SLOT][nf] = *(const short8*)(smem + (BUFB) + ABUF +            \
                    ((((T) * 2 + g_) * 2 + hi) * 64 + px_ * 32 + li32) * 16); \
        }                                                                     \
        _Pragma("unroll")                                                     \
        for (int mf = 0; mf < 2; ++mf)                                        \
            fA[SLOT][mf] = *(const short8*)(smem + (BUFB) +                   \
                    (((wid * 2 + mf + dy_) * 2 + hi) * 34 + li32 + dx_) * 16);\
    } while (0)

#define COMPUTE(BUFB) do {                                                    \
        short8 fA[2][2], fB[2][4];                                            \
        LOADF(BUFB, 0, 0);                                                    \
        __builtin_amdgcn_sched_group_barrier(0x100, 6, 0); /* DS6: tap0 */    \
        __builtin_amdgcn_s_setprio(1);                                        \
        _Pragma("unroll")                                                     \
        for (int s = 0; s < 9; ++s) {                                         \
            const int cur = s & 1, nxt = cur ^ 1;                             \
            if (s < 8) LOADF(BUFB, s + 1, nxt);                               \
            _Pragma("unroll")                                                 \
            for (int mf = 0; mf < 2; ++mf)                                    \
                _Pragma("unroll")                                             \
                for (int nf = 0; nf < 4; ++nf)                                \
                    acc[mf][nf] = __builtin_amdgcn_mfma_f32_32x32x16_bf16(    \
                        fA[cur][mf], fB[cur][nf], acc[mf][nf], 0, 0, 0);      \
            if (s < 8)                                                        \
                __builtin_amdgcn_sched_group_barrier(0x100, 6, 0); /* DS6 */  \
            __builtin_amdgcn_sched_group_barrier(0x008, 8, 0);     /* MFMA8 */\
        }                                                                     \
        __builtin_amdgcn_s_setprio(0);                                        \
    } while (0)

#define SYNC() do {                                                           \
        asm volatile("s_waitcnt vmcnt(0)" ::: "memory");                      \
        __builtin_amdgcn_s_barrier();                                         \
    } while (0)

    // prologue: stage cc=0 into buf0
    STAGE(0, 0);
    SYNC();

#pragma unroll 1
    for (int cc = 0; cc < 32; cc += 2) {
        STAGE(cc + 1, BUFSZ);        // issue early: latency hides under taps
        COMPUTE(0);
        SYNC();
        if (cc + 2 < 32) STAGE(cc + 2, 0);
        COMPUTE(BUFSZ);
        SYNC();
    }

#undef STAGE
#undef LOADF
#undef COMPUTE
#undef SYNC

    // ---- epilogue: interleave phx0/phx1 accs -> contiguous 8-float stores ----
    const float ns = nstr[0];
#pragma unroll
    for (int g = 0; g < 2; ++g) {
        int cout = (cogp * 2 + g) * 32 + li32;
        float dc = dcoef[b * COUT + cout];
        float bs = bias[cout];
#pragma unroll
        for (int mf = 0; mf < 2; ++mf) {
            int ic = y0 + wid * 2 + mf;      // coarse row
            int fr = 2 * ic + phy;           // fine row
            float* op = out + ((size_t)(b * COUT + cout) * RES + fr) * RES;
            const float* npz = noise + fr * RES;
#pragma unroll
            for (int r2 = 0; r2 < 4; ++r2) {
                int fcb = 16 * r2 + 8 * hi;  // fine col base, 8 consecutive
                float nzv[8];
                *(float4v*)&nzv[0] = *(const float4v*)(npz + fcb);
                *(float4v*)&nzv[4] = *(const float4v*)(npz + fcb + 4);
                float f[8];
#pragma unroll
                for (int uu = 0; uu < 4; ++uu) {
#pragma unroll
                    for (int px = 0; px < 2; ++px) {
                        float v = acc[mf][g * 2 + px][r2 * 4 + uu] * dc
                                + nzv[2 * uu + px] * ns + bs;
                        f[2 * uu + px] = (v > 0.f ? v : LRELU * v) * ACT_GAIN;
                    }
                }
                *(float4v*)(op + fcb)     = *(const float4v*)&f[0];
                *(float4v*)(op + fcb + 4) = *(const float4v*)&f[4];
            }
        }
    }
}

extern "C" void kernel_launch(void* const* d_in, const int* in_sizes, int n_in,
                              void* d_out, int out_size, void* d_ws, size_t ws_size,
                              hipStream_t stream) {
    (void)in_sizes; (void)n_in; (void)out_size; (void)ws_size;
    const float* x     = (const float*)d_in[0];
    const float* w     = (const float*)d_in[1];
    const float* aw    = (const float*)d_in[2];
    const float* ab    = (const float*)d_in[3];
    const float* wt    = (const float*)d_in[4];
    const float* bias  = (const float*)d_in[5];
    const float* noise = (const float*)d_in[6];
    const float* nstr  = (const float*)d_in[7];
    float* out = (float*)d_out;

    static bool init = false;
    if (!init) {
        hipFuncSetAttribute(reinterpret_cast<const void*>(conv_mfma),
                            hipFuncAttributeMaxDynamicSharedMemorySize, LDS_TOT);
        init = true;
    }

    char* ws = (char*)d_ws;
    float* styles = (float*)ws;                                   // 32 KB
    float* dcoef  = (float*)(ws + 32768);                         // 32 KB
    float* wsq    = (float*)(ws + 65536);                         // 1 MB
    __hip_bfloat16* gb = (__hip_bfloat16*)(ws + 65536 + 1048576);           // 18.87 MB
    __hip_bfloat16* xb = (__hip_bfloat16*)(ws + 65536 + 1048576 + 18874368); // 18.94 MB

    styles2_kernel<<<dim3(NB, 8), dim3(256), 0, stream>>>(w, aw, ab, styles);
    prep_weights<<<dim3(128), dim3(256), 0, stream>>>(wt, wsq, gb);
    dcoef2_kernel<<<dim3(NB, 8), dim3(256), 0, stream>>>(styles, wsq, dcoef);
    xmod_kernel<<<dim3(34, 4, NB), dim3(256), 0, stream>>>(x, styles, xb);
    conv_mfma<<<dim3(2, 8, NB * 2), dim3(512), LDS_TOT, stream>>>(
        xb, gb, dcoef, bias, noise, nstr, out);
}

// Round 11
// 466.754 us; speedup vs baseline: 1.1941x; 1.0455x over previous
//
#include <hip/hip_runtime.h>
#include <hip/hip_bf16.h>
#include <math.h>

#define CIN   512
#define COUT  512
#define NB    16
#define WD    512
#define HIN   32
#define RES   64
#define LRELU 0.2f
#define ACT_GAIN 1.4142135623730951f

typedef __attribute__((ext_vector_type(8))) short short8;
typedef __attribute__((ext_vector_type(4))) float float4v;
typedef __attribute__((ext_vector_type(16))) float float16v;

// ================= K1: styles (blocks 0..127) || prep_weights (blocks 128..383) ==========
// styles = w @ A^T / sqrt(512) + bias
// gb layout: [cc16][phy2][t9][chi4][cog16][n64][clo8] bf16, n = phx*32 + colo.
// prep: one thread per (co, cc, chi, phy) -> 65536 threads (2x R10 parallelism).
__global__ void k1_styles_prep(const float* __restrict__ w,
                               const float* __restrict__ aw,
                               const float* __restrict__ ab,
                               float* __restrict__ styles,
                               const float* __restrict__ weight,
                               float* __restrict__ wsq,
                               __hip_bfloat16* __restrict__ gb) {
    __shared__ float wsh[WD];
    const int bx = blockIdx.x;
    if (bx < 128) {
        // ---- styles role (verbatim R10 styles2) ----
        int b = bx >> 3;
        int cig = bx & 7;
        int lane = threadIdx.x & 63, wv = threadIdx.x >> 6;
        for (int e = threadIdx.x; e < WD; e += 256) wsh[e] = w[b * WD + e];
        __syncthreads();
        for (int r = 0; r < 16; ++r) {
            int ci = cig * 64 + wv * 16 + r;
            const float* arow = aw + (size_t)ci * WD;
            float acc = 0.f;
            for (int k = lane; k < WD; k += 64) acc += arow[k] * wsh[k];
            for (int off = 32; off; off >>= 1) acc += __shfl_down(acc, off, 64);
            if (lane == 0)
                styles[b * CIN + ci] = acc * 0.04419417382415922f + ab[ci];
        }
        return;
    }
    // ---- prep role ----
    int gid = (bx - 128) * 256 + threadIdx.x;   // 0..65535
    int co = gid & 511;
    int rest = gid >> 9;         // 0..127
    int phy = rest & 1;
    int cig = rest >> 1;         // 0..63
    int cc = cig >> 2, chi = cig & 3;
    int cib = cc * 32 + chi * 8;
    int cog = co >> 5, colo = co & 31;

    float wv[8][3][3];
#pragma unroll
    for (int clo = 0; clo < 8; ++clo) {
        const float* wp = weight + ((size_t)co * CIN + cib + clo) * 9;
        float s = 0.f;
#pragma unroll
        for (int ay = 0; ay < 3; ++ay)
#pragma unroll
            for (int ax = 0; ax < 3; ++ax) {
                float v = wp[ay * 3 + ax];
                wv[clo][ay][ax] = v;
                s += v * v;
            }
        if (phy == 0) wsq[(size_t)co * CIN + cib + clo] = s;
    }

    const float cr[2][3][3] = {
        {{0.f, 0.25f, 0.75f}, {0.75f, 0.75f, 0.25f}, {0.25f, 0.f, 0.f}},
        {{0.f, 0.f, 0.25f},  {0.25f, 0.75f, 0.75f}, {0.75f, 0.25f, 0.f}}};

    float tmp[8][3][3];   // tmp[clo][dy][ax] = sum_ay cr[phy][dy][ay]*wv[clo][ay][ax]
#pragma unroll
    for (int clo = 0; clo < 8; ++clo)
#pragma unroll
        for (int dy = 0; dy < 3; ++dy)
#pragma unroll
            for (int ax = 0; ax < 3; ++ax)
                tmp[clo][dy][ax] = cr[phy][dy][0] * wv[clo][0][ax]
                                 + cr[phy][dy][1] * wv[clo][1][ax]
                                 + cr[phy][dy][2] * wv[clo][2][ax];
#pragma unroll
    for (int phx = 0; phx < 2; ++phx) {
        int n = phx * 32 + colo;
#pragma unroll
        for (int dy = 0; dy < 3; ++dy)
#pragma unroll
            for (int dx = 0; dx < 3; ++dx) {
                int t = dy * 3 + dx;
                short8 sv;
#pragma unroll
                for (int clo = 0; clo < 8; ++clo) {
                    float g = tmp[clo][dy][0] * cr[phx][dx][0]
                            + tmp[clo][dy][1] * cr[phx][dx][1]
                            + tmp[clo][dy][2] * cr[phx][dx][2];
                    __hip_bfloat16 h = __float2bfloat16(g);
                    sv[clo] = *reinterpret_cast<const short*>(&h);
                }
                size_t off = ((((((size_t)cc * 2 + phy) * 9 + t) * 4 + chi)
                               * 16 + cog) * 64 + n) * 8;
                *reinterpret_cast<short8*>(gb + off) = sv;
            }
    }
}

// ================= K2: dcoef (blocks 0..127) || xmod (blocks 128..2303) ==========
// dcoef[b,co] = rsqrt( sum_ci wsq[co,ci]*styles^2 + 1e-8 )
// xmod: x * styles -> channels-last bf16 with zero-padded 34x34 border.
__global__ void k2_dcoef_xmod(const float* __restrict__ styles,
                              const float* __restrict__ wsq,
                              float* __restrict__ dcoef,
                              const float* __restrict__ x,
                              __hip_bfloat16* __restrict__ xb) {
    __shared__ float shf[128 * 36 + 128];   // xmod: xt + ssh; dcoef: first 512 = s2
    const int bx = blockIdx.x;
    if (bx < 128) {
        // ---- dcoef role (verbatim R10 dcoef2) ----
        float* s2 = shf;
        int b = bx >> 3;
        int cog = bx & 7;
        int lane = threadIdx.x & 63, wv = threadIdx.x >> 6;
        for (int e = threadIdx.x; e < CIN; e += 256) {
            float s = styles[b * CIN + e];
            s2[e] = s * s;
        }
        __syncthreads();
        for (int r = 0; r < 16; ++r) {
            int co = cog * 64 + wv * 16 + r;
            const float* qrow = wsq + (size_t)co * CIN;
            float acc = 0.f;
            for (int k = lane; k < CIN; k += 64) acc += qrow[k] * s2[k];
            for (int off = 32; off; off >>= 1) acc += __shfl_down(acc, off, 64);
            if (lane == 0) dcoef[b * COUT + co] = rsqrtf(acc + 1e-8f);
        }
        return;
    }
    // ---- xmod role (verbatim R10 xmod, flattened grid) ----
    float* xt = shf;
    float* ssh = shf + 128 * 36;
    int idx = bx - 128;              // 0..2175
    const int r = idx % 34;          // padded row
    int q = idx / 34;                // 0..63
    const int ci0 = (q & 3) * 128;
    const int b = q >> 2;
    if (threadIdx.x < 128) ssh[threadIdx.x] = styles[b * CIN + ci0 + threadIdx.x];
    const bool inr = (r >= 1) && (r <= 32);
    if (inr) {
        for (int e = threadIdx.x; e < 1024; e += 256) {
            int ci = e >> 3, iw4 = e & 7;
            float4v v = *(const float4v*)(
                x + ((size_t)(b * CIN + ci0 + ci) * HIN + (r - 1)) * HIN + iw4 * 4);
            *(float4v*)(&xt[ci * 36 + iw4 * 4]) = v;
        }
    }
    __syncthreads();
    for (int e = threadIdx.x; e < 544; e += 256) {   // 34 cols * 16 chunks
        int c = e >> 4, t16 = e & 15;
        short8 sv;
#pragma unroll
        for (int u = 0; u < 8; ++u) {
            int ci = t16 * 8 + u;
            float val = 0.f;
            if (inr && c >= 1 && c <= 32) val = xt[ci * 36 + (c - 1)] * ssh[ci];
            __hip_bfloat16 h = __float2bfloat16(val);
            sv[u] = *reinterpret_cast<const short*>(&h);
        }
        *reinterpret_cast<short8*>(
            xb + (((size_t)b * 34 + r) * 34 + c) * CIN + ci0 + t16 * 8) = sv;
    }
}

// ---------------- polyphase implicit-GEMM conv via MFMA bf16 32x32x16 ----------------
// (byte-identical to R10: wave tile 2m x 4n, K-chunk 16, dbuf, SGB pipeline)
#define ABUF 20480
#define BBUF 36864
#define BUFSZ (ABUF + BBUF)          // 57344
#define LDS_TOT (2 * BUFSZ)          // 114688 <= 163840

__global__ __launch_bounds__(512, 1) void conv_mfma(
        const __hip_bfloat16* __restrict__ xb,
        const __hip_bfloat16* __restrict__ gb,
        const float* __restrict__ dcoef,
        const float* __restrict__ bias,
        const float* __restrict__ noise,
        const float* __restrict__ nstr,
        float* __restrict__ out)
{
    extern __shared__ __align__(16) char smem[];
    const int tid = threadIdx.x;
    const int lane = tid & 63;
    const int wid = tid >> 6;        // 0..7
    const int li32 = lane & 31;
    const int hi = lane >> 5;        // 0..1
    const int mb = blockIdx.x;       // 0..1 -> coarse rows y0..y0+15
    const int cogp = blockIdx.y;     // 0..7 -> couts cogp*64..+63
    const int bz = blockIdx.z;       // b*2 + phy
    const int b  = bz >> 1;
    const int phy = bz & 1;
    const int y0 = mb * 16;

    // ---- staging descriptors ----
    int a_goff[3];
#pragma unroll
    for (int k = 0; k < 3; ++k) {
        int n = wid + k * 8;
        int s = n * 64 + lane;          // 16B granule id, valid 0..1223
        if (s > 1223) s = 1223;         // clamp (LDS lands in pad)
        int cr = s / 68;
        int rem = s - cr * 68;
        int kh = rem / 34;
        int col = rem - kh * 34;
        a_goff[k] = ((b * 34 + y0 + cr) * 34 + col) * 512 + kh * 8;
    }
    int b_goff[5];   // BYTE offsets into gb (cc-independent part)
#pragma unroll
    for (int k = 0; k < 5; ++k) {
        int sl = wid + k * 8;
        int t = sl >> 2, g = (sl >> 1) & 1, kh = sl & 1;
        b_goff[k] = (phy * 9 + t) * 65536 + kh * 16384
                  + (cogp * 2 + g) * 1024 + lane * 16;
    }

    float16v acc[2][4];
#pragma unroll
    for (int i = 0; i < 2; ++i)
#pragma unroll
        for (int j = 0; j < 4; ++j) acc[i][j] = (float16v)0.f;

    const char* xg = (const char*)xb;
    const char* wg = (const char*)gb;

#define STAGE(CC, BUFB) do {                                                  \
        _Pragma("unroll")                                                     \
        for (int k = 0; k < 5; ++k) {                                         \
            int sl = wid + k * 8;                                             \
            if (sl < 36) {                                                    \
                long ge = (long)b_goff[k] + (long)((CC) >> 1) * 1179648       \
                        + (long)((CC) & 1) * 32768;                           \
                __builtin_amdgcn_global_load_lds(                             \
                    (const __attribute__((address_space(1))) char*)(wg + ge), \
                    (__attribute__((address_space(3))) char*)(smem + (BUFB) + ABUF + sl * 1024), \
                    16, 0, 0);                                                \
            }                                                                 \
        }                                                                     \
        _Pragma("unroll")                                                     \
        for (int k = 0; k < 3; ++k) {                                         \
            int n = wid + k * 8;                                              \
            if (n < 20) {                                                     \
                long ge = (long)(a_goff[k] + (CC) * 16);                      \
                __builtin_amdgcn_global_load_lds(                             \
                    (const __attribute__((address_space(1))) char*)(xg + ge * 2), \
                    (__attribute__((address_space(3))) char*)(smem + (BUFB) + n * 1024), \
                    16, 0, 0);                                                \
            }                                                                 \
        }                                                                     \
    } while (0)

#define LOADF(BUFB, T, SLOT) do {                                             \
        const int dy_ = (T) / 3, dx_ = (T) - dy_ * 3;                         \
        _Pragma("unroll")                                                     \
        for (int nf = 0; nf < 4; ++nf) {                                      \
            const int g_ = nf >> 1, px_ = nf & 1;                             \
            fB[SLOT][nf] = *(const short8*)(smem + (BUFB) + ABUF +            \
                    ((((T) * 2 + g_) * 2 + hi) * 64 + px_ * 32 + li32) * 16); \
        }                                                                     \
        _Pragma("unroll")                                                     \
        for (int mf = 0; mf < 2; ++mf)                                        \
            fA[SLOT][mf] = *(const short8*)(smem + (BUFB) +                   \
                    (((wid * 2 + mf + dy_) * 2 + hi) * 34 + li32 + dx_) * 16);\
    } while (0)

#define COMPUTE(BUFB) do {                                                    \
        short8 fA[2][2], fB[2][4];                                            \
        LOADF(BUFB, 0, 0);                                                    \
        __builtin_amdgcn_sched_group_barrier(0x100, 6, 0); /* DS6: tap0 */    \
        __builtin_amdgcn_s_setprio(1);                                        \
        _Pragma("unroll")                                                     \
        for (int s = 0; s < 9; ++s) {                                         \
            const int cur = s & 1, nxt = cur ^ 1;                             \
            if (s < 8) LOADF(BUFB, s + 1, nxt);                               \
            _Pragma("unroll")                                                 \
            for (int mf = 0; mf < 2; ++mf)                                    \
                _Pragma("unroll")                                             \
                for (int nf = 0; nf < 4; ++nf)                                \
                    acc[mf][nf] = __builtin_amdgcn_mfma_f32_32x32x16_bf16(    \
                        fA[cur][mf], fB[cur][nf], acc[mf][nf], 0, 0, 0);      \
            if (s < 8)                                                        \
                __builtin_amdgcn_sched_group_barrier(0x100, 6, 0); /* DS6 */  \
            __builtin_amdgcn_sched_group_barrier(0x008, 8, 0);     /* MFMA8 */\
        }                                                                     \
        __builtin_amdgcn_s_setprio(0);                                        \
    } while (0)

#define SYNC() do {                                                           \
        asm volatile("s_waitcnt vmcnt(0)" ::: "memory");                      \
        __builtin_amdgcn_s_barrier();                                         \
    } while (0)

    // prologue: stage cc=0 into buf0
    STAGE(0, 0);
    SYNC();

#pragma unroll 1
    for (int cc = 0; cc < 32; cc += 2) {
        STAGE(cc + 1, BUFSZ);        // issue early: latency hides under taps
        COMPUTE(0);
        SYNC();
        if (cc + 2 < 32) STAGE(cc + 2, 0);
        COMPUTE(BUFSZ);
        SYNC();
    }

#undef STAGE
#undef LOADF
#undef COMPUTE
#undef SYNC

    // ---- epilogue: interleave phx0/phx1 accs -> contiguous 8-float stores ----
    const float ns = nstr[0];
#pragma unroll
    for (int g = 0; g < 2; ++g) {
        int cout = (cogp * 2 + g) * 32 + li32;
        float dc = dcoef[b * COUT + cout];
        float bs = bias[cout];
#pragma unroll
        for (int mf = 0; mf < 2; ++mf) {
            int ic = y0 + wid * 2 + mf;      // coarse row
            int fr = 2 * ic + phy;           // fine row
            float* op = out + ((size_t)(b * COUT + cout) * RES + fr) * RES;
            const float* npz = noise + fr * RES;
#pragma unroll
            for (int r2 = 0; r2 < 4; ++r2) {
                int fcb = 16 * r2 + 8 * hi;  // fine col base, 8 consecutive
                float nzv[8];
                *(float4v*)&nzv[0] = *(const float4v*)(npz + fcb);
                *(float4v*)&nzv[4] = *(const float4v*)(npz + fcb + 4);
                float f[8];
#pragma unroll
                for (int uu = 0; uu < 4; ++uu) {
#pragma unroll
                    for (int px = 0; px < 2; ++px) {
                        float v = acc[mf][g * 2 + px][r2 * 4 + uu] * dc
                                + nzv[2 * uu + px] * ns + bs;
                        f[2 * uu + px] = (v > 0.f ? v : LRELU * v) * ACT_GAIN;
                    }
                }
                *(float4v*)(op + fcb)     = *(const float4v*)&f[0];
                *(float4v*)(op + fcb + 4) = *(const float4v*)&f[4];
            }
        }
    }
}

extern "C" void kernel_launch(void* const* d_in, const int* in_sizes, int n_in,
                              void* d_out, int out_size, void* d_ws, size_t ws_size,
                              hipStream_t stream) {
    (void)in_sizes; (void)n_in; (void)out_size; (void)ws_size;
    const float* x     = (const float*)d_in[0];
    const float* w     = (const float*)d_in[1];
    const float* aw    = (const float*)d_in[2];
    const float* ab    = (const float*)d_in[3];
    const float* wt    = (const float*)d_in[4];
    const float* bias  = (const float*)d_in[5];
    const float* noise = (const float*)d_in[6];
    const float* nstr  = (const float*)d_in[7];
    float* out = (float*)d_out;

    static bool init = false;
    if (!init) {
        hipFuncSetAttribute(reinterpret_cast<const void*>(conv_mfma),
                            hipFuncAttributeMaxDynamicSharedMemorySize, LDS_TOT);
        init = true;
    }

    char* ws = (char*)d_ws;
    float* styles = (float*)ws;                                   // 32 KB
    float* dcoef  = (float*)(ws + 32768);                         // 32 KB
    float* wsq    = (float*)(ws + 65536);                         // 1 MB
    __hip_bfloat16* gb = (__hip_bfloat16*)(ws + 65536 + 1048576);           // 18.87 MB
    __hip_bfloat16* xb = (__hip_bfloat16*)(ws + 65536 + 1048576 + 18874368); // 18.94 MB

    k1_styles_prep<<<dim3(384), dim3(256), 0, stream>>>(
        w, aw, ab, styles, wt, wsq, gb);
    k2_dcoef_xmod<<<dim3(2304), dim3(256), 0, stream>>>(
        styles, wsq, dcoef, x, xb);
    conv_mfma<<<dim3(2, 8, NB * 2), dim3(512), LDS_TOT, stream>>>(
        xb, gb, dcoef, bias, noise, nstr, out);
}